// Round 1
// baseline (316.475 us; speedup 1.0000x reference)
//
#include <hip/hip_runtime.h>
#include <math.h>

#define B_ 128
#define A_ 8732
#define C_ 21
#define APB 256                       // anchors per block (kernel 1)
#define NBLK ((A_ + APB - 1) / APB)   // 35 blocks per row

// ws layout:
//   [0..15]    float scalars[4]: {loc_loss, conf_pos, conf_neg, pad}
//   [16..527]  int row_num_pos[B_]
//   [1024.. ]  float ce_neg[B_*A_]  (CE for negatives, 0 for positives)

__global__ __launch_bounds__(256) void k_ce(
        const float* __restrict__ conf, const float* __restrict__ loc,
        const int* __restrict__ lab, const float* __restrict__ gloc,
        float* __restrict__ ce_neg, float* __restrict__ scal,
        int* __restrict__ row_np)
{
    __shared__ float sConf[APB * C_];   // 21504 B
    const int b   = blockIdx.y;
    const int a0  = blockIdx.x * APB;
    const int n   = min(APB, A_ - a0);
    const int tid = threadIdx.x;

    // stage confidences tile, coalesced float4 (tile base is 16B-aligned: 84*256 % 16 == 0, 84*8732 % 16 == 0)
    {
        const size_t base = ((size_t)b * A_ + a0) * C_;
        const int total = n * C_;
        const int n4 = total >> 2;
        const float4* src4 = (const float4*)(conf + base);
        float4* dst4 = (float4*)sConf;
        for (int i = tid; i < n4; i += 256) dst4[i] = src4[i];
        for (int i = (n4 << 2) + tid; i < total; i += 256) sConf[i] = conf[base + i];
    }
    __syncthreads();

    float pce = 0.f, lloss = 0.f;
    int pcnt = 0;
    if (tid < n) {
        const int a = a0 + tid;
        float v[C_];
        #pragma unroll
        for (int j = 0; j < C_; j++) v[j] = sConf[tid * C_ + j];
        float m = v[0];
        #pragma unroll
        for (int j = 1; j < C_; j++) m = fmaxf(m, v[j]);
        float s = 0.f;
        #pragma unroll
        for (int j = 0; j < C_; j++) s += __expf(v[j] - m);
        const int L = lab[(size_t)b * A_ + a];
        const float ce = __logf(s) + m - v[L];
        const bool pos = (L > 0);
        ce_neg[(size_t)b * A_ + a] = pos ? 0.f : ce;
        if (pos) {
            pce = ce;
            pcnt = 1;
            const float4 lv = ((const float4*)loc)[(size_t)b * A_ + a];
            const float4 gv = ((const float4*)gloc)[(size_t)b * A_ + a];
            float dx = lv.x - gv.x, dy = lv.y - gv.y, dz = lv.z - gv.z, dw = lv.w - gv.w;
            float ax = fabsf(dx), ay = fabsf(dy), az = fabsf(dz), aw = fabsf(dw);
            lloss  = (ax < 1.f) ? 0.5f * dx * dx : ax - 0.5f;
            lloss += (ay < 1.f) ? 0.5f * dy * dy : ay - 0.5f;
            lloss += (az < 1.f) ? 0.5f * dz * dz : az - 0.5f;
            lloss += (aw < 1.f) ? 0.5f * dw * dw : aw - 0.5f;
        }
    }

    // wave (64) reduce, then cross-wave via LDS
    #pragma unroll
    for (int off = 32; off > 0; off >>= 1) {
        pce   += __shfl_down(pce, off);
        lloss += __shfl_down(lloss, off);
        pcnt  += __shfl_down(pcnt, off);
    }
    __shared__ float wf[4], wl[4];
    __shared__ int wc[4];
    const int wave = tid >> 6, lane = tid & 63;
    if (lane == 0) { wf[wave] = pce; wl[wave] = lloss; wc[wave] = pcnt; }
    __syncthreads();
    if (tid == 0) {
        float fp = wf[0] + wf[1] + wf[2] + wf[3];
        float fl = wl[0] + wl[1] + wl[2] + wl[3];
        int   c  = wc[0] + wc[1] + wc[2] + wc[3];
        if (fl != 0.f) atomicAdd(&scal[0], fl);
        if (fp != 0.f) atomicAdd(&scal[1], fp);
        if (c)         atomicAdd(&row_np[b], c);
    }
}

// exact top-k sum per row via 4-pass radix select on float bit patterns (all CE >= 0)
__global__ __launch_bounds__(1024) void k_select(
        const float* __restrict__ ce_neg, const int* __restrict__ row_np,
        float* __restrict__ scal)
{
    const int b = blockIdx.x;
    const int tid = threadIdx.x;
    const float* ce = ce_neg + (size_t)b * A_;
    const int np = row_np[b];
    const int k = min(3 * np, A_ - np);
    if (k <= 0) return;   // uniform across block

    __shared__ unsigned int hist[256];
    __shared__ unsigned int s_bin, s_kk;

    unsigned int prefix = 0;
    unsigned int kk = (unsigned)k;
    for (int pass = 0; pass < 4; pass++) {
        const int shift = 24 - 8 * pass;
        if (tid < 256) hist[tid] = 0;
        __syncthreads();
        for (int i = tid; i < A_; i += 1024) {
            unsigned key = __float_as_uint(ce[i]);
            bool match = (pass == 0) || ((key >> (shift + 8)) == prefix);
            if (match) atomicAdd(&hist[(key >> shift) & 0xFF], 1u);
        }
        __syncthreads();
        if (tid == 0) {
            unsigned cum = 0;
            int m = 255;
            for (; m > 0; m--) {
                if (cum + hist[m] >= kk) break;
                cum += hist[m];
            }
            s_bin = (unsigned)m;
            s_kk  = kk - cum;
        }
        __syncthreads();
        prefix = (prefix << 8) | s_bin;
        kk = s_kk;
    }

    const unsigned kthk = prefix;
    const float kthv = __uint_as_float(prefix);
    float sum = 0.f;
    unsigned cnt = 0;
    for (int i = tid; i < A_; i += 1024) {
        float v = ce[i];
        if (__float_as_uint(v) > kthk) { sum += v; cnt++; }
    }
    #pragma unroll
    for (int off = 32; off > 0; off >>= 1) {
        sum += __shfl_down(sum, off);
        cnt += __shfl_down(cnt, off);
    }
    __shared__ float wsums[16];
    __shared__ unsigned wcnts[16];
    const int wave = tid >> 6, lane = tid & 63;
    if (lane == 0) { wsums[wave] = sum; wcnts[wave] = cnt; }
    __syncthreads();
    if (tid == 0) {
        float S = 0.f; unsigned Cn = 0;
        #pragma unroll
        for (int w = 0; w < 16; w++) { S += wsums[w]; Cn += wcnts[w]; }
        float r = S + (float)(k - (int)Cn) * kthv;
        atomicAdd(&scal[2], r);
    }
}

__global__ __launch_bounds__(128) void k_final(
        const int* __restrict__ row_np, const float* __restrict__ scal,
        float* __restrict__ out)
{
    const int tid = threadIdx.x;
    int v = row_np[tid];
    #pragma unroll
    for (int off = 32; off > 0; off >>= 1) v += __shfl_down(v, off);
    __shared__ int w[2];
    if ((tid & 63) == 0) w[tid >> 6] = v;
    __syncthreads();
    if (tid == 0) {
        int total = w[0] + w[1];
        out[0] = (scal[0] + scal[1] + scal[2]) / (float)total;
    }
}

extern "C" void kernel_launch(void* const* d_in, const int* in_sizes, int n_in,
                              void* d_out, int out_size, void* d_ws, size_t ws_size,
                              hipStream_t stream) {
    const float* conf = (const float*)d_in[0];   // (B, A, C) f32
    const float* loc  = (const float*)d_in[1];   // (B, A, 4) f32
    const int*   lab  = (const int*)d_in[2];     // (B, A) i32
    const float* gloc = (const float*)d_in[3];   // (B, A, 4) f32

    float* scal   = (float*)d_ws;
    int*   row_np = (int*)((char*)d_ws + 16);
    float* ce_neg = (float*)((char*)d_ws + 1024);

    hipMemsetAsync(d_ws, 0, 1024, stream);   // zero scalars + row counters (ws is poisoned)

    dim3 g1(NBLK, B_);
    k_ce<<<g1, 256, 0, stream>>>(conf, loc, lab, gloc, ce_neg, scal, row_np);
    k_select<<<B_, 1024, 0, stream>>>(ce_neg, row_np, scal);
    k_final<<<1, 128, 0, stream>>>(row_np, scal, (float*)d_out);
}

// Round 2
// 195.369 us; speedup vs baseline: 1.6199x; 1.6199x over previous
//
#include <hip/hip_runtime.h>
#include <math.h>

#define B_ 128
#define A_ 8732
#define C_ 21
#define APB 256                       // anchors per block (kernel 1)
#define NBLK ((A_ + APB - 1) / APB)   // 35 blocks per row
#define NPART (B_ * NBLK)             // 4480 partials

// ws layout (bytes):
//   [0          .. 17920)   float part_loc[4480]
//   [17920      .. 35840)   float part_pce[4480]
//   [35840      .. 53760)   int   part_np[4480]
//   [53760      .. 54272)   float row_cneg[128]
//   [54272      .. 54784)   int   row_np[128]
//   [57344      ..     )    float ce_neg[128*8732]
#define OFF_PLOC 0
#define OFF_PPCE 17920
#define OFF_PNP  35840
#define OFF_RCN  53760
#define OFF_RNP  54272
#define OFF_CEN  57344

__global__ __launch_bounds__(256) void k_ce(
        const float* __restrict__ conf, const float* __restrict__ loc,
        const int* __restrict__ lab, const float* __restrict__ gloc,
        float* __restrict__ ce_neg, float* __restrict__ part_loc,
        float* __restrict__ part_pce, int* __restrict__ part_np)
{
    __shared__ float sConf[APB * C_];   // 21504 B
    const int b   = blockIdx.y;
    const int a0  = blockIdx.x * APB;
    const int n   = min(APB, A_ - a0);
    const int tid = threadIdx.x;

    // stage confidences tile, coalesced float4 (tile base is 16B-aligned)
    {
        const size_t base = ((size_t)b * A_ + a0) * C_;
        const int total = n * C_;
        const int n4 = total >> 2;
        const float4* src4 = (const float4*)(conf + base);
        float4* dst4 = (float4*)sConf;
        for (int i = tid; i < n4; i += 256) dst4[i] = src4[i];
        for (int i = (n4 << 2) + tid; i < total; i += 256) sConf[i] = conf[base + i];
    }
    __syncthreads();

    float pce = 0.f, lloss = 0.f;
    int pcnt = 0;
    if (tid < n) {
        const int a = a0 + tid;
        float v[C_];
        #pragma unroll
        for (int j = 0; j < C_; j++) v[j] = sConf[tid * C_ + j];
        float m = v[0];
        #pragma unroll
        for (int j = 1; j < C_; j++) m = fmaxf(m, v[j]);
        float s = 0.f;
        #pragma unroll
        for (int j = 0; j < C_; j++) s += __expf(v[j] - m);
        const int L = lab[(size_t)b * A_ + a];
        const float ce = __logf(s) + m - v[L];
        const bool pos = (L > 0);
        ce_neg[(size_t)b * A_ + a] = pos ? 0.f : ce;
        if (pos) {
            pce = ce;
            pcnt = 1;
            const float4 lv = ((const float4*)loc)[(size_t)b * A_ + a];
            const float4 gv = ((const float4*)gloc)[(size_t)b * A_ + a];
            float dx = lv.x - gv.x, dy = lv.y - gv.y, dz = lv.z - gv.z, dw = lv.w - gv.w;
            float ax = fabsf(dx), ay = fabsf(dy), az = fabsf(dz), aw = fabsf(dw);
            lloss  = (ax < 1.f) ? 0.5f * dx * dx : ax - 0.5f;
            lloss += (ay < 1.f) ? 0.5f * dy * dy : ay - 0.5f;
            lloss += (az < 1.f) ? 0.5f * dz * dz : az - 0.5f;
            lloss += (aw < 1.f) ? 0.5f * dw * dw : aw - 0.5f;
        }
    }

    // wave (64) reduce, then cross-wave via LDS; NO global atomics
    #pragma unroll
    for (int off = 32; off > 0; off >>= 1) {
        pce   += __shfl_down(pce, off);
        lloss += __shfl_down(lloss, off);
        pcnt  += __shfl_down(pcnt, off);
    }
    __shared__ float wf[4], wl[4];
    __shared__ int wc[4];
    const int wave = tid >> 6, lane = tid & 63;
    if (lane == 0) { wf[wave] = pce; wl[wave] = lloss; wc[wave] = pcnt; }
    __syncthreads();
    if (tid == 0) {
        const int bid = b * NBLK + blockIdx.x;
        part_loc[bid] = wl[0] + wl[1] + wl[2] + wl[3];
        part_pce[bid] = wf[0] + wf[1] + wf[2] + wf[3];
        part_np[bid]  = wc[0] + wc[1] + wc[2] + wc[3];
    }
}

// block-wide sum of a uint + float pair, broadcast to all threads
__device__ __forceinline__ void blk_sum(unsigned vc, float vs,
                                        unsigned* shc, float* shs,
                                        int wave, int lane,
                                        unsigned* outc, float* outs)
{
    #pragma unroll
    for (int off = 32; off > 0; off >>= 1) {
        vc += __shfl_down(vc, off);
        vs += __shfl_down(vs, off);
    }
    __syncthreads();                    // protect LDS reuse across calls
    if (lane == 0) { shc[wave] = vc; shs[wave] = vs; }
    __syncthreads();
    unsigned tc = 0; float ts = 0.f;
    #pragma unroll
    for (int w = 0; w < 16; w++) { tc += shc[w]; ts += shs[w]; }
    *outc = tc; *outs = ts;
}

// exact per-row top-k sum via atomic-free binary search on float bit patterns
__global__ __launch_bounds__(1024) void k_select(
        const float* __restrict__ ce_neg, const int* __restrict__ part_np,
        float* __restrict__ row_cneg, int* __restrict__ row_np)
{
    const int b = blockIdx.x;
    const int tid = threadIdx.x;
    const int wave = tid >> 6, lane = tid & 63;
    const float* ce = ce_neg + (size_t)b * A_;

    __shared__ unsigned shc[16];
    __shared__ float shs[16];
    __shared__ int s_np;

    // row num_pos from per-block partials (35 values, wave 0)
    if (wave == 0) {
        int v = (lane < NBLK) ? part_np[b * NBLK + lane] : 0;
        #pragma unroll
        for (int off = 32; off > 0; off >>= 1) v += __shfl_down(v, off);
        if (lane == 0) s_np = v;
    }

    // each thread holds its 9 keys in registers (bit patterns; all CE >= 0)
    unsigned keys[9];
    #pragma unroll
    for (int j = 0; j < 9; j++) {
        const int i = tid + j * 1024;
        keys[j] = (i < A_) ? __float_as_uint(ce[i]) : 0u;
    }
    __syncthreads();
    const int np = s_np;
    const int k = min(3 * np, A_ - np);

    float result = 0.f;
    if (k > 0) {
        // threshold-0 pass: count & sum of all strictly-positive keys
        unsigned c0 = 0; float s0 = 0.f;
        #pragma unroll
        for (int j = 0; j < 9; j++)
            if (keys[j] > 0u) { c0++; s0 += __uint_as_float(keys[j]); }
        unsigned cnt0; float sum0;
        blk_sum(c0, s0, shc, shs, wave, lane, &cnt0, &sum0);

        if (cnt0 < (unsigned)k) {
            result = sum0;   // fewer than k nonzero CEs: kth value is 0
        } else {
            unsigned lo = 0u, hi = 0x7F800000u;   // f(lo) >= k, f(hi) = 0 < k
            while (hi - lo > 1u) {
                const unsigned mid = lo + ((hi - lo) >> 1);
                unsigned c = 0;
                #pragma unroll
                for (int j = 0; j < 9; j++) c += (keys[j] > mid) ? 1u : 0u;
                unsigned tot; float dummy;
                blk_sum(c, 0.f, shc, shs, wave, lane, &tot, &dummy);
                if (tot >= (unsigned)k) lo = mid; else hi = mid;
            }
            // hi == bit pattern of kth-largest value
            unsigned c = 0; float s = 0.f;
            #pragma unroll
            for (int j = 0; j < 9; j++)
                if (keys[j] > hi) { c++; s += __uint_as_float(keys[j]); }
            unsigned cg; float sg;
            blk_sum(c, s, shc, shs, wave, lane, &cg, &sg);
            result = sg + (float)(k - (int)cg) * __uint_as_float(hi);
        }
    }

    if (tid == 0) { row_cneg[b] = result; row_np[b] = np; }
}

__global__ __launch_bounds__(1024) void k_final(
        const float* __restrict__ part_loc, const float* __restrict__ part_pce,
        const float* __restrict__ row_cneg, const int* __restrict__ row_np,
        float* __restrict__ out)
{
    const int tid = threadIdx.x;
    const int wave = tid >> 6, lane = tid & 63;
    float s = 0.f;
    for (int i = tid; i < NPART; i += 1024) s += part_loc[i] + part_pce[i];
    int n = 0;
    if (tid < B_) { s += row_cneg[tid]; n = row_np[tid]; }
    #pragma unroll
    for (int off = 32; off > 0; off >>= 1) {
        s += __shfl_down(s, off);
        n += __shfl_down(n, off);
    }
    __shared__ float ws_[16];
    __shared__ int wn_[16];
    if (lane == 0) { ws_[wave] = s; wn_[wave] = n; }
    __syncthreads();
    if (tid == 0) {
        float S = 0.f; int N = 0;
        #pragma unroll
        for (int w = 0; w < 16; w++) { S += ws_[w]; N += wn_[w]; }
        out[0] = S / (float)N;
    }
}

extern "C" void kernel_launch(void* const* d_in, const int* in_sizes, int n_in,
                              void* d_out, int out_size, void* d_ws, size_t ws_size,
                              hipStream_t stream) {
    const float* conf = (const float*)d_in[0];   // (B, A, C) f32
    const float* loc  = (const float*)d_in[1];   // (B, A, 4) f32
    const int*   lab  = (const int*)d_in[2];     // (B, A) i32
    const float* gloc = (const float*)d_in[3];   // (B, A, 4) f32

    char* ws = (char*)d_ws;
    float* part_loc = (float*)(ws + OFF_PLOC);
    float* part_pce = (float*)(ws + OFF_PPCE);
    int*   part_np  = (int*)(ws + OFF_PNP);
    float* row_cneg = (float*)(ws + OFF_RCN);
    int*   row_np   = (int*)(ws + OFF_RNP);
    float* ce_neg   = (float*)(ws + OFF_CEN);

    dim3 g1(NBLK, B_);
    k_ce<<<g1, 256, 0, stream>>>(conf, loc, lab, gloc, ce_neg,
                                 part_loc, part_pce, part_np);
    k_select<<<B_, 1024, 0, stream>>>(ce_neg, part_np, row_cneg, row_np);
    k_final<<<1, 1024, 0, stream>>>(part_loc, part_pce, row_cneg, row_np,
                                    (float*)d_out);
}